// Round 10
// baseline (227.754 us; speedup 1.0000x reference)
//
#include <hip/hip_runtime.h>
#include <stdint.h>

typedef unsigned short u16;
typedef unsigned int u32;
typedef __attribute__((ext_vector_type(8))) short s16x8;   // 8 bf16 (4 VGPRs)
typedef __attribute__((ext_vector_type(4))) float fx4;     // 4 fp32 acc

#define AS_GLOBAL __attribute__((address_space(1)))
#define AS_LDS    __attribute__((address_space(3)))

__device__ __forceinline__ void g2l16(const u16* g, u16* l) {
  __builtin_amdgcn_global_load_lds((const AS_GLOBAL unsigned int*)g,
                                   (AS_LDS unsigned int*)l, 16, 0, 0);
}
__device__ __forceinline__ u16 f2bf(float f) {   // fp32 -> bf16 RNE
  u32 u = __float_as_uint(f);
  u += 0x7FFF + ((u >> 16) & 1);
  return (u16)(u >> 16);
}
// hardware packed fp32->bf16 RNE (1 VOP3 for 2 elements)
__device__ __forceinline__ u32 pkcvt(float a, float b) {
  u32 r;
  asm("v_cvt_pk_bf16_f32 %0, %1, %2" : "=v"(r) : "v"(a), "v"(b));
  return r;
}

// ---------------------------------------------------------------- converts (one launch)
// y 0..2: activations (q,k,v), 1048576 float4 each. y 3..6: weights, 262144 each.
__global__ __launch_bounds__(256) void cvt7(
    const float* __restrict__ q, const float* __restrict__ k, const float* __restrict__ v,
    const float* __restrict__ Wq, const float* __restrict__ Wk,
    const float* __restrict__ Wv, const float* __restrict__ Wo,
    u16* qb, u16* kb, u16* vb, u16* wqb, u16* wkb, u16* wvb, u16* wob) {
  const int y = blockIdx.y;
  const int n4 = y < 3 ? 1048576 : 262144;
  int i = blockIdx.x * 256 + threadIdx.x;
  if (i >= n4) return;
  const float* src = y == 0 ? q : y == 1 ? k : y == 2 ? v
                   : y == 3 ? Wq : y == 4 ? Wk : y == 5 ? Wv : Wo;
  u16* dst = y == 0 ? qb : y == 1 ? kb : y == 2 ? vb
           : y == 3 ? wqb : y == 4 ? wkb : y == 5 ? wvb : wob;
  float4 f = ((const float4*)src)[i];
  ushort4 o; o.x = f2bf(f.x); o.y = f2bf(f.y); o.z = f2bf(f.z); o.w = f2bf(f.w);
  ((ushort4*)dst)[i] = o;
}

// ---------------------------------------------------------------- fused QKV GEMM
// z==0 (Q): scaled by sm_scale*log2e, layout [B,H,S,Hd].
// z==1 (K): layout [B,H,S,Hd].
// z==2 (V): written DIRECTLY as V^T [B,H,Hd,S].
// Round-9: double-buffered LDS staging, ONE barrier per K-step. kb unrolled by 2
// with NAMED buffers (static LDS addressing; no dynamic cur index):
//   stage(kb+1 -> alt buf) ; compute(kb from cur buf) ; __syncthreads()
// __syncthreads() drains own vmcnt (stage loads, covered by the 16 MFMAs) and
// lgkm, then barriers -> next iter's buffer is staged block-wide.
__global__ __launch_bounds__(256) void gemm_qkv(
    const u16* __restrict__ Aq, const u16* __restrict__ Ak, const u16* __restrict__ Av,
    const u16* __restrict__ Wq, const u16* __restrict__ Wk, const u16* __restrict__ Wv,
    const float* __restrict__ bq, const float* __restrict__ bk, const float* __restrict__ bv,
    u16* __restrict__ Oq, u16* __restrict__ Ok, u16* __restrict__ Ovt)
{
  constexpr int K = 1024;
  __shared__ u16 As0[128 * 32];
  __shared__ u16 Bs0[128 * 32];
  __shared__ u16 As1[128 * 32];
  __shared__ u16 Bs1[128 * 32];
  const int z = blockIdx.z;
  const u16* A = z == 0 ? Aq : z == 1 ? Ak : Av;
  const u16* W = z == 0 ? Wq : z == 1 ? Wk : Wv;
  const float* bias = z == 0 ? bq : z == 1 ? bk : bv;
  const float scale = z == 0 ? 0.180336880f : 1.0f;  // 0.125 * log2(e)

  const int bm = blockIdx.x, bn = blockIdx.y;
  const int tid = threadIdx.x;
  const int lane = tid & 63, wave = tid >> 6;
  const int quad = lane >> 4, col = lane & 15;
  const int wm = wave >> 1, wn = wave & 1;

  const int L0 = tid, L1 = 256 + tid;
  const int r0 = L0 >> 2, c0 = (L0 & 3) ^ ((r0 >> 1) & 3);
  const int r1 = L1 >> 2, c1 = (L1 & 3) ^ ((r1 >> 1) & 3);
  const u16* gA0 = A + (bm * 128 + r0) * K + c0 * 8;
  const u16* gA1 = A + (bm * 128 + r1) * K + c1 * 8;
  const u16* gB0 = W + (bn * 128 + r0) * K + c0 * 8;
  const u16* gB1 = W + (bn * 128 + r1) * K + c1 * 8;

  const int aRow = wm * 64 + col;
  const int bRow = wn * 64 + col;

  fx4 zero = {0.f, 0.f, 0.f, 0.f};
  fx4 acc[4][4];
#pragma unroll
  for (int i = 0; i < 4; ++i)
#pragma unroll
    for (int j = 0; j < 4; ++j) acc[i][j] = zero;

#define STAGE_QKV(AS, BS, kb)                 \
  do {                                        \
    g2l16(gA0 + (kb) * 32, (AS) + L0 * 8);    \
    g2l16(gA1 + (kb) * 32, (AS) + L1 * 8);    \
    g2l16(gB0 + (kb) * 32, (BS) + L0 * 8);    \
    g2l16(gB1 + (kb) * 32, (BS) + L1 * 8);    \
  } while (0)

#define COMPUTE_QKV(AS, BS)                                                         \
  do {                                                                              \
    s16x8 af[4], bf[4];                                                             \
    _Pragma("unroll") for (int mt = 0; mt < 4; ++mt) {                              \
      int row = aRow + mt * 16;                                                     \
      int ch = row * 4 + (quad ^ ((row >> 1) & 3));                                 \
      af[mt] = *(const s16x8*)((AS) + ch * 8);                                      \
    }                                                                               \
    _Pragma("unroll") for (int nt = 0; nt < 4; ++nt) {                              \
      int row = bRow + nt * 16;                                                     \
      int ch = row * 4 + (quad ^ ((row >> 1) & 3));                                 \
      bf[nt] = *(const s16x8*)((BS) + ch * 8);                                      \
    }                                                                               \
    _Pragma("unroll") for (int mt = 0; mt < 4; ++mt)                                \
      _Pragma("unroll") for (int nt = 0; nt < 4; ++nt)                              \
        acc[mt][nt] = __builtin_amdgcn_mfma_f32_16x16x32_bf16(af[mt], bf[nt],       \
                                                              acc[mt][nt], 0, 0, 0);\
  } while (0)

  STAGE_QKV(As0, Bs0, 0);
  __syncthreads();
  for (int kb = 0; kb < K / 32; kb += 2) {
    if (kb + 1 < K / 32) STAGE_QKV(As1, Bs1, kb + 1);
    COMPUTE_QKV(As0, Bs0);
    __syncthreads();
    if (kb + 2 < K / 32) STAGE_QKV(As0, Bs0, kb + 2);
    COMPUTE_QKV(As1, Bs1);
    __syncthreads();
  }
#undef STAGE_QKV
#undef COMPUTE_QKV

  if (z == 2) {
    // direct V^T store: per (mt,nt) the 4 acc regs are 4 CONSECUTIVE s values
    // at fixed (h,hd) -> one packed 8B store. Vt[((b*16+h)*64+hd)*2048 + s].
#pragma unroll
    for (int nt = 0; nt < 4; ++nt) {
      int n = bn * 128 + wn * 64 + nt * 16 + col;
      float bvv = bias[n];
      int h = n >> 6, hd = n & 63;
#pragma unroll
      for (int mt = 0; mt < 4; ++mt) {
        int mbase = bm * 128 + wm * 64 + mt * 16 + quad * 4;
        int b = mbase >> 11, s = mbase & 2047;
        uint2 w;
        w.x = pkcvt(acc[mt][nt][0] + bvv, acc[mt][nt][1] + bvv);
        w.y = pkcvt(acc[mt][nt][2] + bvv, acc[mt][nt][3] + bvv);
        *(uint2*)(Ovt + ((size_t)((b * 16 + h) * 64 + hd)) * 2048 + s) = w;
      }
    }
  } else {
    u16* outB = z == 0 ? Oq : Ok;
#pragma unroll
    for (int nt = 0; nt < 4; ++nt) {
      int n = bn * 128 + wn * 64 + nt * 16 + col;
      float bvv = bias[n];
#pragma unroll
      for (int mt = 0; mt < 4; ++mt) {
        int mbase = bm * 128 + wm * 64 + mt * 16 + quad * 4;
#pragma unroll
        for (int reg = 0; reg < 4; ++reg) {
          int m = mbase + reg;
          float v = (acc[mt][nt][reg] + bvv) * scale;
          int b = m >> 11, s = m & 2047;
          int h = n >> 6, hd = n & 63;
          outB[((b * 16 + h) * 2048 + s) * 64 + hd] = f2bf(v);
        }
      }
    }
  }
}

// ---------------------------------------------------------------- out-proj GEMM (128x64 tile, fp32 out)
// Round-9: same double-buffered one-barrier pipeline as gemm_qkv.
__global__ __launch_bounds__(256) void gemm_out(
    const u16* __restrict__ A, const u16* __restrict__ W,
    const float* __restrict__ bias, float* __restrict__ outF)
{
  constexpr int K = 1024;
  __shared__ u16 As0[128 * 32];
  __shared__ u16 Bs0[64 * 32];
  __shared__ u16 As1[128 * 32];
  __shared__ u16 Bs1[64 * 32];
  const int bm = blockIdx.x, bn = blockIdx.y;
  const int tid = threadIdx.x;
  const int lane = tid & 63, wave = tid >> 6;
  const int quad = lane >> 4, col = lane & 15;
  const int wm = wave >> 1, wn = wave & 1;

  const int L0 = tid, L1 = 256 + tid;
  const int r0 = L0 >> 2, c0 = (L0 & 3) ^ ((r0 >> 1) & 3);
  const int r1 = L1 >> 2, c1 = (L1 & 3) ^ ((r1 >> 1) & 3);
  const u16* gA0 = A + (bm * 128 + r0) * K + c0 * 8;
  const u16* gA1 = A + (bm * 128 + r1) * K + c1 * 8;
  const u16* gB0 = W + (bn * 64 + r0) * K + c0 * 8;   // Bs: 256 chunks, 1/thread

  const int aRow = wm * 64 + col;
  const int bRow = wn * 32 + col;

  fx4 zero = {0.f, 0.f, 0.f, 0.f};
  fx4 acc[4][2];
#pragma unroll
  for (int i = 0; i < 4; ++i)
#pragma unroll
    for (int j = 0; j < 2; ++j) acc[i][j] = zero;

#define STAGE_OUT(AS, BS, kb)                 \
  do {                                        \
    g2l16(gA0 + (kb) * 32, (AS) + L0 * 8);    \
    g2l16(gA1 + (kb) * 32, (AS) + L1 * 8);    \
    g2l16(gB0 + (kb) * 32, (BS) + L0 * 8);    \
  } while (0)

#define COMPUTE_OUT(AS, BS)                                                         \
  do {                                                                              \
    s16x8 af[4], bf[2];                                                             \
    _Pragma("unroll") for (int mt = 0; mt < 4; ++mt) {                              \
      int row = aRow + mt * 16;                                                     \
      int ch = row * 4 + (quad ^ ((row >> 1) & 3));                                 \
      af[mt] = *(const s16x8*)((AS) + ch * 8);                                      \
    }                                                                               \
    _Pragma("unroll") for (int nt = 0; nt < 2; ++nt) {                              \
      int row = bRow + nt * 16;                                                     \
      int ch = row * 4 + (quad ^ ((row >> 1) & 3));                                 \
      bf[nt] = *(const s16x8*)((BS) + ch * 8);                                      \
    }                                                                               \
    _Pragma("unroll") for (int mt = 0; mt < 4; ++mt)                                \
      _Pragma("unroll") for (int nt = 0; nt < 2; ++nt)                              \
        acc[mt][nt] = __builtin_amdgcn_mfma_f32_16x16x32_bf16(af[mt], bf[nt],       \
                                                              acc[mt][nt], 0, 0, 0);\
  } while (0)

  STAGE_OUT(As0, Bs0, 0);
  __syncthreads();
  for (int kb = 0; kb < K / 32; kb += 2) {
    if (kb + 1 < K / 32) STAGE_OUT(As1, Bs1, kb + 1);
    COMPUTE_OUT(As0, Bs0);
    __syncthreads();
    if (kb + 2 < K / 32) STAGE_OUT(As0, Bs0, kb + 2);
    COMPUTE_OUT(As1, Bs1);
    __syncthreads();
  }
#undef STAGE_OUT
#undef COMPUTE_OUT

#pragma unroll
  for (int nt = 0; nt < 2; ++nt) {
    int n = bn * 64 + wn * 32 + nt * 16 + col;
    float bvv = bias[n];
#pragma unroll
    for (int mt = 0; mt < 4; ++mt) {
      int mbase = bm * 128 + wm * 64 + mt * 16 + quad * 4;
#pragma unroll
      for (int reg = 0; reg < 4; ++reg)
        outF[(mbase + reg) * 1024 + n] = acc[mt][nt][reg] + bvv;
    }
  }
}

// ---------------------------------------------------------------- flash attention
// (round-8 structure, byte-identical — PASS at 59.1 µs)
// QBLK 128, 8 waves (512 thr). grid (16 qt, 32 bh). K LDS-staged single-buffered,
// prefetched one iter ahead; V async-staged under QK^T.
// LDS 64KB: Vs 16K + Ks 16K + P 8x4K = 32768 u16.
__global__ __launch_bounds__(512, 4) void flash_attn(
    const u16* __restrict__ Qp, const u16* __restrict__ Kp,
    const u16* __restrict__ Vt, u16* __restrict__ ctx)
{
  __shared__ u16 sh[32768];  // u16: Vs [0,8192) ; Ks [8192,16384) ; P [16384,32768)
  const int qt = blockIdx.x, bh = blockIdx.y;
  const int tid = threadIdx.x, lane = tid & 63, wave = tid >> 6;
  const int quad = lane >> 4, col = lane & 15;
  const int wm = wave >> 1, wn = wave & 1;

  const u16* Qb = Qp + ((size_t)bh * 2048 + qt * 128) * 64;
  const u16* Kb = Kp + (size_t)bh * 2048 * 64;
  const u16* Vb = Vt + (size_t)bh * 64 * 2048;

  s16x8 qf[2][2];   // B-operand: Q[m=lane&15][d=quad*8+j], halves of d=64
#pragma unroll
  for (int mt = 0; mt < 2; ++mt)
#pragma unroll
    for (int h = 0; h < 2; ++h)
      qf[mt][h] = *(const s16x8*)(Qb + (wm * 32 + mt * 16 + col) * 64 + h * 32 + quad * 8);

  fx4 zero = {0.f, 0.f, 0.f, 0.f};
  fx4 acc_o[2][4], acc_l[2];
#pragma unroll
  for (int mt = 0; mt < 2; ++mt) {
    acc_l[mt] = zero;
#pragma unroll
    for (int dt = 0; dt < 4; ++dt) acc_o[mt][dt] = zero;
  }
  s16x8 ones;
#pragma unroll
  for (int j = 0; j < 8; ++j) ones[j] = (short)0x3F80;  // bf16 1.0

  u16* Vs = sh;
  u16* Ks = sh + 8192;
  u16* Pw = sh + 16384 + wave * 2048;  // per-wave P[m=32][n=64], 16B-chunk swizzled

  // V-stage: 1024 chunks (64 d x 16 c), 512 threads -> 2 each. PRE-SWIZZLED
  // global source, linear LDS dest: phys slot (d, p) holds V^T[d][p ^ (d&15)].
  const u16* vsrc[2];
#pragma unroll
  for (int i = 0; i < 2; ++i) {
    int d = wave * 8 + i * 4 + (lane >> 4);
    int cs = (lane & 15) ^ (d & 15);
    vsrc[i] = Vb + d * 2048 + cs * 8;
  }

  // K-stage: 1024 chunks (128 rows x 8 chunks), 2 per thread.
  // phys chunk (d, c) holds logical chunk (c ^ (d&7)) of K row n0+d.
  const u16* ksrc[2];
  u16* kdst[2];
#pragma unroll
  for (int i = 0; i < 2; ++i) {
    int idx = wave * 128 + i * 64 + lane;
    int d = idx >> 3, c = idx & 7;
    ksrc[i] = Kb + d * 64 + (c ^ (d & 7)) * 8;
    kdst[i] = Ks + (wave * 128 + i * 64) * 8;   // wave-uniform base, +lane*16B by HW
  }

  // prologue: stage K(0), drain own loads; loop-top barrier = block guarantee.
#pragma unroll
  for (int i = 0; i < 2; ++i) g2l16(ksrc[i], kdst[i]);
  asm volatile("s_waitcnt vmcnt(0)" ::: "memory");

  for (int kv = 0; kv < 16; ++kv) {
    const int n0 = kv * 128;
    __builtin_amdgcn_s_barrier();        // A: PV(i-1) done with Vs; K(i) staged
    // issue async V staging; latency hides under QK^T
#pragma unroll
    for (int i = 0; i < 2; ++i)
      g2l16(vsrc[i] + n0, Vs + (wave * 8 + i * 4) * 128);

    // scores S^T = K*Q^T, K from LDS; softmax; P write (b64)
    __builtin_amdgcn_s_setprio(1);
#pragma unroll
    for (int nt = 0; nt < 4; ++nt) {
      const int r = wn * 64 + nt * 16 + col;
      const u16* krow = Ks + r * 64;
      const int x = r & 7;
      s16x8 k0 = *(const s16x8*)(krow + ((quad ^ x) << 3));
      s16x8 k1 = *(const s16x8*)(krow + (((4 ^ quad) ^ x) << 3));
#pragma unroll
      for (int mt = 0; mt < 2; ++mt) {
        fx4 s = __builtin_amdgcn_mfma_f32_16x16x32_bf16(k0, qf[mt][0], zero, 0, 0, 0);
        s = __builtin_amdgcn_mfma_f32_16x16x32_bf16(k1, qf[mt][1], s, 0, 0, 0);
        int m = mt * 16 + col;
        int cch = 2 * nt + (quad >> 1);
        uint2 w;
        w.x = pkcvt(exp2f(s[0]), exp2f(s[1]));
        w.y = pkcvt(exp2f(s[2]), exp2f(s[3]));
        *(uint2*)(Pw + m * 64 + ((cch ^ (m & 7))) * 8 + (quad & 1) * 4) = w;
      }
    }
    __builtin_amdgcn_s_setprio(0);

    // V(i) landed (covered by QK^T); P ds_writes drained
    asm volatile("s_waitcnt vmcnt(0)" ::: "memory");
    asm volatile("s_waitcnt lgkmcnt(0)" ::: "memory");
    __builtin_amdgcn_s_barrier();        // B: Vs staged block-wide; K reads done

    // K buffer now free block-wide: issue K(i+1) staging (covered by PV)
    if (kv < 15) {
#pragma unroll
      for (int i = 0; i < 2; ++i)
        g2l16(ksrc[i] + (kv + 1) * 8192, kdst[i]);
    }

    // PV: A = P (own wave region), B = V^T rows; l via ones-MFMA
    __builtin_amdgcn_s_setprio(1);
#pragma unroll
    for (int ks = 0; ks < 2; ++ks) {
      s16x8 pf[2];
#pragma unroll
      for (int mt = 0; mt < 2; ++mt)
        pf[mt] = *(const s16x8*)(Pw + (mt * 16 + col) * 64 + ((4 * ks + quad) ^ (col & 7)) * 8);
#pragma unroll
      for (int dt = 0; dt < 4; ++dt) {
        s16x8 vf = *(const s16x8*)(Vs + (dt * 16 + col) * 128 + ((wn * 8 + 4 * ks + quad) ^ col) * 8);
#pragma unroll
        for (int mt = 0; mt < 2; ++mt)
          acc_o[mt][dt] = __builtin_amdgcn_mfma_f32_16x16x32_bf16(pf[mt], vf, acc_o[mt][dt], 0, 0, 0);
      }
#pragma unroll
      for (int mt = 0; mt < 2; ++mt)
        acc_l[mt] = __builtin_amdgcn_mfma_f32_16x16x32_bf16(pf[mt], ones, acc_l[mt], 0, 0, 0);
    }
    __builtin_amdgcn_s_setprio(0);

    // drain own K(i+1) before next barrier A (its cover was the PV phase)
    asm volatile("s_waitcnt vmcnt(0)" ::: "memory");
  }

  // cross-wave (wn) reduction of O,l partials via LDS, then epilogue by wn==0
  __syncthreads();
  float* buf = (float*)sh;
  if (wn == 1) {
#pragma unroll
    for (int mt = 0; mt < 2; ++mt) {
#pragma unroll
      for (int dt = 0; dt < 4; ++dt)
#pragma unroll
        for (int e = 0; e < 4; ++e)
          buf[wm * 2560 + ((mt * 4 + dt) * 4 + e) * 64 + lane] = acc_o[mt][dt][e];
#pragma unroll
      for (int e = 0; e < 4; ++e)
        buf[wm * 2560 + (32 + mt * 4 + e) * 64 + lane] = acc_l[mt][e];
    }
  }
  __syncthreads();
  if (wn == 0) {
    const int b = bh >> 4, h = bh & 15;
#pragma unroll
    for (int mt = 0; mt < 2; ++mt) {
      fx4 rl;
#pragma unroll
      for (int e = 0; e < 4; ++e) {
        float l = acc_l[mt][e] + buf[wm * 2560 + (32 + mt * 4 + e) * 64 + lane];
        rl[e] = 1.0f / l;
      }
#pragma unroll
      for (int dt = 0; dt < 4; ++dt)
#pragma unroll
        for (int e = 0; e < 4; ++e) {
          float v = (acc_o[mt][dt][e] + buf[wm * 2560 + ((mt * 4 + dt) * 4 + e) * 64 + lane]) * rl[e];
          int s = qt * 128 + wm * 32 + mt * 16 + quad * 4 + e;
          ctx[((size_t)(b * 2048 + s)) * 1024 + h * 64 + dt * 16 + col] = f2bf(v);
        }
    }
  }
}

// ---------------------------------------------------------------- launch
extern "C" void kernel_launch(void* const* d_in, const int* in_sizes, int n_in,
                              void* d_out, int out_size, void* d_ws, size_t ws_size,
                              hipStream_t stream) {
  const float* q  = (const float*)d_in[0];
  const float* k  = (const float*)d_in[1];
  const float* v  = (const float*)d_in[2];
  const float* Wq = (const float*)d_in[3];
  const float* bq = (const float*)d_in[4];
  const float* Wk = (const float*)d_in[5];
  const float* bk = (const float*)d_in[6];
  const float* Wv = (const float*)d_in[7];
  const float* bv = (const float*)d_in[8];
  const float* Wo = (const float*)d_in[9];
  const float* bo = (const float*)d_in[10];
  float* out = (float*)d_out;

  char* ws = (char*)d_ws;
  const size_t MB = 1u << 20;
  u16* qb  = (u16*)(ws + 0 * MB);
  u16* kb  = (u16*)(ws + 8 * MB);
  u16* vb  = (u16*)(ws + 16 * MB);
  u16* wqb = (u16*)(ws + 24 * MB);
  u16* wkb = (u16*)(ws + 26 * MB);
  u16* wvb = (u16*)(ws + 28 * MB);
  u16* wob = (u16*)(ws + 30 * MB);
  u16* Qp  = (u16*)(ws + 32 * MB);
  u16* Kp  = (u16*)(ws + 40 * MB);
  u16* Vtp = (u16*)(ws + 56 * MB);
  u16* ctx = (u16*)(ws + 64 * MB);   // total 72 MB

  cvt7<<<dim3(4096, 7), 256, 0, stream>>>(q, k, v, Wq, Wk, Wv, Wo,
                                          qb, kb, vb, wqb, wkb, wvb, wob);

  gemm_qkv<<<dim3(32, 8, 3), 256, 0, stream>>>(qb, kb, vb, wqb, wkb, wvb,
                                               bq, bk, bv, Qp, Kp, Vtp);
  flash_attn<<<dim3(16, 32), 512, 0, stream>>>(Qp, Kp, Vtp, ctx);
  gemm_out<<<dim3(32, 16), 256, 0, stream>>>(ctx, wob, bo, out);
}

// Round 15
// 221.641 us; speedup vs baseline: 1.0276x; 1.0276x over previous
//
#include <hip/hip_runtime.h>
#include <stdint.h>

typedef unsigned short u16;
typedef unsigned int u32;
typedef __attribute__((ext_vector_type(8))) short s16x8;   // 8 bf16 (4 VGPRs)
typedef __attribute__((ext_vector_type(4))) float fx4;     // 4 fp32 acc

#define AS_GLOBAL __attribute__((address_space(1)))
#define AS_LDS    __attribute__((address_space(3)))

__device__ __forceinline__ void g2l16(const u16* g, u16* l) {
  __builtin_amdgcn_global_load_lds((const AS_GLOBAL unsigned int*)g,
                                   (AS_LDS unsigned int*)l, 16, 0, 0);
}
__device__ __forceinline__ u16 f2bf(float f) {   // fp32 -> bf16 RNE
  u32 u = __float_as_uint(f);
  u += 0x7FFF + ((u >> 16) & 1);
  return (u16)(u >> 16);
}
// hardware packed fp32->bf16 RNE (1 VOP3 for 2 elements).
// NOTE (r12/r14 lesson): inputs must NOT come directly from a raw v_exp_f32 —
// the hazard recognizer does not insert TRANS->VALU waits before inline asm.
// libm exp2f's fixup ops provide the needed distance; keep exp2f here.
__device__ __forceinline__ u32 pkcvt(float a, float b) {
  u32 r;
  asm("v_cvt_pk_bf16_f32 %0, %1, %2" : "=v"(r) : "v"(a), "v"(b));
  return r;
}

// ---------------------------------------------------------------- converts (fused)
__global__ __launch_bounds__(256) void cvt3(const float* __restrict__ a, const float* __restrict__ b,
                                            const float* __restrict__ c, u16* oa, u16* ob, u16* oc, int n4) {
  const float* src = blockIdx.y == 0 ? a : blockIdx.y == 1 ? b : c;
  u16* dst = blockIdx.y == 0 ? oa : blockIdx.y == 1 ? ob : oc;
  int i = blockIdx.x * 256 + threadIdx.x;
  if (i >= n4) return;
  float4 f = ((const float4*)src)[i];
  ushort4 o; o.x = f2bf(f.x); o.y = f2bf(f.y); o.z = f2bf(f.z); o.w = f2bf(f.w);
  ((ushort4*)dst)[i] = o;
}
__global__ __launch_bounds__(256) void cvt4(const float* __restrict__ a, const float* __restrict__ b,
                                            const float* __restrict__ c, const float* __restrict__ d,
                                            u16* oa, u16* ob, u16* oc, u16* od, int n4) {
  const float* src = blockIdx.y == 0 ? a : blockIdx.y == 1 ? b : blockIdx.y == 2 ? c : d;
  u16* dst = blockIdx.y == 0 ? oa : blockIdx.y == 1 ? ob : blockIdx.y == 2 ? oc : od;
  int i = blockIdx.x * 256 + threadIdx.x;
  if (i >= n4) return;
  float4 f = ((const float4*)src)[i];
  ushort4 o; o.x = f2bf(f.x); o.y = f2bf(f.y); o.z = f2bf(f.z); o.w = f2bf(f.w);
  ((ushort4*)dst)[i] = o;
}

// ---------------------------------------------------------------- fused QKV GEMM
// z==0 (Q): scaled by sm_scale*log2e, layout [B,H,S,Hd].
// z==1 (K): layout [B,H,S,Hd].
// z==2 (V): written DIRECTLY as V^T [B,H,Hd,S] (transpose_v kernel eliminated).
__global__ __launch_bounds__(256) void gemm_qkv(
    const u16* __restrict__ Aq, const u16* __restrict__ Ak, const u16* __restrict__ Av,
    const u16* __restrict__ Wq, const u16* __restrict__ Wk, const u16* __restrict__ Wv,
    const float* __restrict__ bq, const float* __restrict__ bk, const float* __restrict__ bv,
    u16* __restrict__ Oq, u16* __restrict__ Ok, u16* __restrict__ Ovt)
{
  constexpr int K = 1024;
  __shared__ u16 As[128 * 32];
  __shared__ u16 Bs[128 * 32];
  const int z = blockIdx.z;
  const u16* A = z == 0 ? Aq : z == 1 ? Ak : Av;
  const u16* W = z == 0 ? Wq : z == 1 ? Wk : Wv;
  const float* bias = z == 0 ? bq : z == 1 ? bk : bv;
  const float scale = z == 0 ? 0.180336880f : 1.0f;  // 0.125 * log2(e)

  const int bm = blockIdx.x, bn = blockIdx.y;
  const int tid = threadIdx.x;
  const int lane = tid & 63, wave = tid >> 6;
  const int quad = lane >> 4, col = lane & 15;
  const int wm = wave >> 1, wn = wave & 1;

  const int L0 = tid, L1 = 256 + tid;
  const int r0 = L0 >> 2, c0 = (L0 & 3) ^ ((r0 >> 1) & 3);
  const int r1 = L1 >> 2, c1 = (L1 & 3) ^ ((r1 >> 1) & 3);
  const u16* gA0 = A + (bm * 128 + r0) * K + c0 * 8;
  const u16* gA1 = A + (bm * 128 + r1) * K + c1 * 8;
  const u16* gB0 = W + (bn * 128 + r0) * K + c0 * 8;
  const u16* gB1 = W + (bn * 128 + r1) * K + c1 * 8;
  u16* lA0 = As + L0 * 8; u16* lA1 = As + L1 * 8;
  u16* lB0 = Bs + L0 * 8; u16* lB1 = Bs + L1 * 8;

  const int aRow = wm * 64 + col;
  const int bRow = wn * 64 + col;

  fx4 zero = {0.f, 0.f, 0.f, 0.f};
  fx4 acc[4][4];
#pragma unroll
  for (int i = 0; i < 4; ++i)
#pragma unroll
    for (int j = 0; j < 4; ++j) acc[i][j] = zero;

  for (int kb = 0; kb < K / 32; ++kb) {
    __syncthreads();
    g2l16(gA0 + kb * 32, lA0);
    g2l16(gA1 + kb * 32, lA1);
    g2l16(gB0 + kb * 32, lB0);
    g2l16(gB1 + kb * 32, lB1);
    __syncthreads();
    s16x8 af[4], bf[4];
#pragma unroll
    for (int mt = 0; mt < 4; ++mt) {
      int row = aRow + mt * 16;
      int ch = row * 4 + (quad ^ ((row >> 1) & 3));
      af[mt] = *(const s16x8*)(As + ch * 8);
    }
#pragma unroll
    for (int nt = 0; nt < 4; ++nt) {
      int row = bRow + nt * 16;
      int ch = row * 4 + (quad ^ ((row >> 1) & 3));
      bf[nt] = *(const s16x8*)(Bs + ch * 8);
    }
#pragma unroll
    for (int mt = 0; mt < 4; ++mt)
#pragma unroll
      for (int nt = 0; nt < 4; ++nt)
        acc[mt][nt] = __builtin_amdgcn_mfma_f32_16x16x32_bf16(af[mt], bf[nt], acc[mt][nt], 0, 0, 0);
  }

  if (z == 2) {
    // direct V^T store: per (mt,nt) the 4 acc regs are 4 CONSECUTIVE s values
    // at fixed (h,hd) -> one packed 8B store. Vt[((b*16+h)*64+hd)*2048 + s].
#pragma unroll
    for (int nt = 0; nt < 4; ++nt) {
      int n = bn * 128 + wn * 64 + nt * 16 + col;
      float bvv = bias[n];
      int h = n >> 6, hd = n & 63;
#pragma unroll
      for (int mt = 0; mt < 4; ++mt) {
        int mbase = bm * 128 + wm * 64 + mt * 16 + quad * 4;
        int b = mbase >> 11, s = mbase & 2047;
        uint2 w;
        w.x = pkcvt(acc[mt][nt][0] + bvv, acc[mt][nt][1] + bvv);
        w.y = pkcvt(acc[mt][nt][2] + bvv, acc[mt][nt][3] + bvv);
        *(uint2*)(Ovt + ((size_t)((b * 16 + h) * 64 + hd)) * 2048 + s) = w;
      }
    }
  } else {
    u16* outB = z == 0 ? Oq : Ok;
#pragma unroll
    for (int nt = 0; nt < 4; ++nt) {
      int n = bn * 128 + wn * 64 + nt * 16 + col;
      float bvv = bias[n];
#pragma unroll
      for (int mt = 0; mt < 4; ++mt) {
        int mbase = bm * 128 + wm * 64 + mt * 16 + quad * 4;
#pragma unroll
        for (int reg = 0; reg < 4; ++reg) {
          int m = mbase + reg;
          float v = (acc[mt][nt][reg] + bvv) * scale;
          int b = m >> 11, s = m & 2047;
          int h = n >> 6, hd = n & 63;
          outB[((b * 16 + h) * 2048 + s) * 64 + hd] = f2bf(v);
        }
      }
    }
  }
}

// ---------------------------------------------------------------- out-proj GEMM (128x64 tile, fp32 out)
__global__ __launch_bounds__(256) void gemm_out(
    const u16* __restrict__ A, const u16* __restrict__ W,
    const float* __restrict__ bias, float* __restrict__ outF)
{
  constexpr int K = 1024;
  __shared__ u16 As[128 * 32];
  __shared__ u16 Bs[64 * 32];
  const int bm = blockIdx.x, bn = blockIdx.y;
  const int tid = threadIdx.x;
  const int lane = tid & 63, wave = tid >> 6;
  const int quad = lane >> 4, col = lane & 15;
  const int wm = wave >> 1, wn = wave & 1;

  const int L0 = tid, L1 = 256 + tid;
  const int r0 = L0 >> 2, c0 = (L0 & 3) ^ ((r0 >> 1) & 3);
  const int r1 = L1 >> 2, c1 = (L1 & 3) ^ ((r1 >> 1) & 3);
  const u16* gA0 = A + (bm * 128 + r0) * K + c0 * 8;
  const u16* gA1 = A + (bm * 128 + r1) * K + c1 * 8;
  const u16* gB0 = W + (bn * 64 + r0) * K + c0 * 8;   // Bs: 256 chunks, 1/thread
  u16* lA0 = As + L0 * 8; u16* lA1 = As + L1 * 8;
  u16* lB0 = Bs + L0 * 8;

  const int aRow = wm * 64 + col;
  const int bRow = wn * 32 + col;

  fx4 zero = {0.f, 0.f, 0.f, 0.f};
  fx4 acc[4][2];
#pragma unroll
  for (int i = 0; i < 4; ++i)
#pragma unroll
    for (int j = 0; j < 2; ++j) acc[i][j] = zero;

  for (int kb = 0; kb < K / 32; ++kb) {
    __syncthreads();
    g2l16(gA0 + kb * 32, lA0);
    g2l16(gA1 + kb * 32, lA1);
    g2l16(gB0 + kb * 32, lB0);
    __syncthreads();
    s16x8 af[4], bf[2];
#pragma unroll
    for (int mt = 0; mt < 4; ++mt) {
      int row = aRow + mt * 16;
      int ch = row * 4 + (quad ^ ((row >> 1) & 3));
      af[mt] = *(const s16x8*)(As + ch * 8);
    }
#pragma unroll
    for (int nt = 0; nt < 2; ++nt) {
      int row = bRow + nt * 16;
      int ch = row * 4 + (quad ^ ((row >> 1) & 3));
      bf[nt] = *(const s16x8*)(Bs + ch * 8);
    }
#pragma unroll
    for (int mt = 0; mt < 4; ++mt)
#pragma unroll
      for (int nt = 0; nt < 2; ++nt)
        acc[mt][nt] = __builtin_amdgcn_mfma_f32_16x16x32_bf16(af[mt], bf[nt], acc[mt][nt], 0, 0, 0);
  }

#pragma unroll
  for (int nt = 0; nt < 2; ++nt) {
    int n = bn * 64 + wn * 32 + nt * 16 + col;
    float bvv = bias[n];
#pragma unroll
    for (int mt = 0; mt < 4; ++mt) {
      int mbase = bm * 128 + wm * 64 + mt * 16 + quad * 4;
#pragma unroll
      for (int reg = 0; reg < 4; ++reg)
        outF[(mbase + reg) * 1024 + n] = acc[mt][nt][reg] + bvv;
    }
  }
}

// ---------------------------------------------------------------- flash attention
// (round-8 exact — measured 59.1 µs, MfmaUtil 26.6, VALUBusy 56)
// QBLK 128, 8 waves (512 thr). grid (16 qt, 32 bh). K LDS-staged single-buffered,
// prefetched one iter ahead; V async-staged under QK^T.
// LDS 64KB: Vs 16K + Ks 16K + P 8x4K = 32768 u16.
__global__ __launch_bounds__(512, 4) void flash_attn(
    const u16* __restrict__ Qp, const u16* __restrict__ Kp,
    const u16* __restrict__ Vt, u16* __restrict__ ctx)
{
  __shared__ u16 sh[32768];  // u16: Vs [0,8192) ; Ks [8192,16384) ; P [16384,32768)
  const int qt = blockIdx.x, bh = blockIdx.y;
  const int tid = threadIdx.x, lane = tid & 63, wave = tid >> 6;
  const int quad = lane >> 4, col = lane & 15;
  const int wm = wave >> 1, wn = wave & 1;

  const u16* Qb = Qp + ((size_t)bh * 2048 + qt * 128) * 64;
  const u16* Kb = Kp + (size_t)bh * 2048 * 64;
  const u16* Vb = Vt + (size_t)bh * 64 * 2048;

  s16x8 qf[2][2];   // B-operand: Q[m=lane&15][d=quad*8+j], halves of d=64
#pragma unroll
  for (int mt = 0; mt < 2; ++mt)
#pragma unroll
    for (int h = 0; h < 2; ++h)
      qf[mt][h] = *(const s16x8*)(Qb + (wm * 32 + mt * 16 + col) * 64 + h * 32 + quad * 8);

  fx4 zero = {0.f, 0.f, 0.f, 0.f};
  fx4 acc_o[2][4], acc_l[2];
#pragma unroll
  for (int mt = 0; mt < 2; ++mt) {
    acc_l[mt] = zero;
#pragma unroll
    for (int dt = 0; dt < 4; ++dt) acc_o[mt][dt] = zero;
  }
  s16x8 ones;
#pragma unroll
  for (int j = 0; j < 8; ++j) ones[j] = (short)0x3F80;  // bf16 1.0

  u16* Vs = sh;
  u16* Ks = sh + 8192;
  u16* Pw = sh + 16384 + wave * 2048;  // per-wave P[m=32][n=64], 16B-chunk swizzled

  // V-stage: 1024 chunks (64 d x 16 c), 512 threads -> 2 each. PRE-SWIZZLED
  // global source, linear LDS dest: phys slot (d, p) holds V^T[d][p ^ (d&15)].
  const u16* vsrc[2];
#pragma unroll
  for (int i = 0; i < 2; ++i) {
    int d = wave * 8 + i * 4 + (lane >> 4);
    int cs = (lane & 15) ^ (d & 15);
    vsrc[i] = Vb + d * 2048 + cs * 8;
  }

  // K-stage: 1024 chunks (128 rows x 8 chunks), 2 per thread.
  // phys chunk (d, c) holds logical chunk (c ^ (d&7)) of K row n0+d.
  const u16* ksrc[2];
  u16* kdst[2];
#pragma unroll
  for (int i = 0; i < 2; ++i) {
    int idx = wave * 128 + i * 64 + lane;
    int d = idx >> 3, c = idx & 7;
    ksrc[i] = Kb + d * 64 + (c ^ (d & 7)) * 8;
    kdst[i] = Ks + (wave * 128 + i * 64) * 8;   // wave-uniform base, +lane*16B by HW
  }

  // prologue: stage K(0), drain own loads; loop-top barrier = block guarantee.
#pragma unroll
  for (int i = 0; i < 2; ++i) g2l16(ksrc[i], kdst[i]);
  asm volatile("s_waitcnt vmcnt(0)" ::: "memory");

  for (int kv = 0; kv < 16; ++kv) {
    const int n0 = kv * 128;
    __builtin_amdgcn_s_barrier();        // A: PV(i-1) done with Vs; K(i) staged
    // issue async V staging; latency hides under QK^T
#pragma unroll
    for (int i = 0; i < 2; ++i)
      g2l16(vsrc[i] + n0, Vs + (wave * 8 + i * 4) * 128);

    // scores S^T = K*Q^T, K from LDS; softmax; P write (b64)
    __builtin_amdgcn_s_setprio(1);
#pragma unroll
    for (int nt = 0; nt < 4; ++nt) {
      const int r = wn * 64 + nt * 16 + col;
      const u16* krow = Ks + r * 64;
      const int x = r & 7;
      s16x8 k0 = *(const s16x8*)(krow + ((quad ^ x) << 3));
      s16x8 k1 = *(const s16x8*)(krow + (((4 ^ quad) ^ x) << 3));
#pragma unroll
      for (int mt = 0; mt < 2; ++mt) {
        fx4 s = __builtin_amdgcn_mfma_f32_16x16x32_bf16(k0, qf[mt][0], zero, 0, 0, 0);
        s = __builtin_amdgcn_mfma_f32_16x16x32_bf16(k1, qf[mt][1], s, 0, 0, 0);
        int m = mt * 16 + col;
        int cch = 2 * nt + (quad >> 1);
        uint2 w;
        w.x = pkcvt(exp2f(s[0]), exp2f(s[1]));
        w.y = pkcvt(exp2f(s[2]), exp2f(s[3]));
        *(uint2*)(Pw + m * 64 + ((cch ^ (m & 7))) * 8 + (quad & 1) * 4) = w;
      }
    }
    __builtin_amdgcn_s_setprio(0);

    // V(i) landed (covered by QK^T); P ds_writes drained
    asm volatile("s_waitcnt vmcnt(0)" ::: "memory");
    asm volatile("s_waitcnt lgkmcnt(0)" ::: "memory");
    __builtin_amdgcn_s_barrier();        // B: Vs staged block-wide; K reads done

    // K buffer now free block-wide: issue K(i+1) staging (covered by PV)
    if (kv < 15) {
#pragma unroll
      for (int i = 0; i < 2; ++i)
        g2l16(ksrc[i] + (kv + 1) * 8192, kdst[i]);
    }

    // PV: A = P (own wave region), B = V^T rows; l via ones-MFMA
    __builtin_amdgcn_s_setprio(1);
#pragma unroll
    for (int ks = 0; ks < 2; ++ks) {
      s16x8 pf[2];
#pragma unroll
      for (int mt = 0; mt < 2; ++mt)
        pf[mt] = *(const s16x8*)(Pw + (mt * 16 + col) * 64 + ((4 * ks + quad) ^ (col & 7)) * 8);
#pragma unroll
      for (int dt = 0; dt < 4; ++dt) {
        s16x8 vf = *(const s16x8*)(Vs + (dt * 16 + col) * 128 + ((wn * 8 + 4 * ks + quad) ^ col) * 8);
#pragma unroll
        for (int mt = 0; mt < 2; ++mt)
          acc_o[mt][dt] = __builtin_amdgcn_mfma_f32_16x16x32_bf16(pf[mt], vf, acc_o[mt][dt], 0, 0, 0);
      }
#pragma unroll
      for (int mt = 0; mt < 2; ++mt)
        acc_l[mt] = __builtin_amdgcn_mfma_f32_16x16x32_bf16(pf[mt], ones, acc_l[mt], 0, 0, 0);
    }
    __builtin_amdgcn_s_setprio(0);

    // drain own K(i+1) before next barrier A (its cover was the PV phase)
    asm volatile("s_waitcnt vmcnt(0)" ::: "memory");
  }

  // cross-wave (wn) reduction of O,l partials via LDS, then epilogue by wn==0
  __syncthreads();
  float* buf = (float*)sh;
  if (wn == 1) {
#pragma unroll
    for (int mt = 0; mt < 2; ++mt) {
#pragma unroll
      for (int dt = 0; dt < 4; ++dt)
#pragma unroll
        for (int e = 0; e < 4; ++e)
          buf[wm * 2560 + ((mt * 4 + dt) * 4 + e) * 64 + lane] = acc_o[mt][dt][e];
#pragma unroll
      for (int e = 0; e < 4; ++e)
        buf[wm * 2560 + (32 + mt * 4 + e) * 64 + lane] = acc_l[mt][e];
    }
  }
  __syncthreads();
  if (wn == 0) {
    const int b = bh >> 4, h = bh & 15;
#pragma unroll
    for (int mt = 0; mt < 2; ++mt) {
      fx4 rl;
#pragma unroll
      for (int e = 0; e < 4; ++e) {
        float l = acc_l[mt][e] + buf[wm * 2560 + (32 + mt * 4 + e) * 64 + lane];
        rl[e] = 1.0f / l;
      }
#pragma unroll
      for (int dt = 0; dt < 4; ++dt)
#pragma unroll
        for (int e = 0; e < 4; ++e) {
          float v = (acc_o[mt][dt][e] + buf[wm * 2560 + ((mt * 4 + dt) * 4 + e) * 64 + lane]) * rl[e];
          int s = qt * 128 + wm * 32 + mt * 16 + quad * 4 + e;
          ctx[((size_t)(b * 2048 + s)) * 1024 + h * 64 + dt * 16 + col] = f2bf(v);
        }
    }
  }
}

// ---------------------------------------------------------------- launch
extern "C" void kernel_launch(void* const* d_in, const int* in_sizes, int n_in,
                              void* d_out, int out_size, void* d_ws, size_t ws_size,
                              hipStream_t stream) {
  const float* q  = (const float*)d_in[0];
  const float* k  = (const float*)d_in[1];
  const float* v  = (const float*)d_in[2];
  const float* Wq = (const float*)d_in[3];
  const float* bq = (const float*)d_in[4];
  const float* Wk = (const float*)d_in[5];
  const float* bk = (const float*)d_in[6];
  const float* Wv = (const float*)d_in[7];
  const float* bv = (const float*)d_in[8];
  const float* Wo = (const float*)d_in[9];
  const float* bo = (const float*)d_in[10];
  float* out = (float*)d_out;

  char* ws = (char*)d_ws;
  const size_t MB = 1u << 20;
  u16* qb  = (u16*)(ws + 0 * MB);
  u16* kb  = (u16*)(ws + 8 * MB);
  u16* vb  = (u16*)(ws + 16 * MB);
  u16* wqb = (u16*)(ws + 24 * MB);
  u16* wkb = (u16*)(ws + 26 * MB);
  u16* wvb = (u16*)(ws + 28 * MB);
  u16* wob = (u16*)(ws + 30 * MB);
  u16* Qp  = (u16*)(ws + 32 * MB);
  u16* Kp  = (u16*)(ws + 40 * MB);
  u16* Vtp = (u16*)(ws + 56 * MB);
  u16* ctx = (u16*)(ws + 64 * MB);   // total 72 MB

  cvt3<<<dim3(4096, 3), 256, 0, stream>>>(q, k, v, qb, kb, vb, 1048576);
  cvt4<<<dim3(1024, 4), 256, 0, stream>>>(Wq, Wk, Wv, Wo, wqb, wkb, wvb, wob, 262144);

  gemm_qkv<<<dim3(32, 8, 3), 256, 0, stream>>>(qb, kb, vb, wqb, wkb, wvb,
                                               bq, bk, bv, Qp, Kp, Vtp);
  flash_attn<<<dim3(16, 32), 512, 0, stream>>>(Qp, Kp, Vtp, ctx);
  gemm_out<<<dim3(32, 16), 256, 0, stream>>>(ctx, wob, bo, out);
}